// Round 3
// baseline (165.947 us; speedup 1.0000x reference)
//
#include <hip/hip_runtime.h>
#include <stdint.h>

#define S      56
#define NC     20
#define NBX    2
#define NCELL  (S*S)          // 3136
#define NBOXES (NCELL*NBX)    // 6272
#define DIM    94080          // NCELL*NC + NCELL*NBX + NCELL*NBX*4
#define BD1    62720          // NCELL*NC
#define BD2    68992          // BD1 + NCELL*NBX
#define CAND   256
#define MAXOUT 30
#define NTHR   1024
#define NWAVE  (NTHR/64)      // 16

__device__ __forceinline__ uint64_t make_key(uint32_t sb, int idx) {
    // higher score -> higher key; equal score -> lower idx -> higher key
    return ((uint64_t)sb << 13) | (uint64_t)(8191 - idx);
}

__device__ __forceinline__ uint64_t pack_sc(float v, int cls) {
    // total order: higher product wins; equal product -> lower class wins
    return ((uint64_t)__float_as_uint(v) << 8) | (uint64_t)(255 - cls);
}

__global__ __launch_bounds__(NTHR) void det_kernel(const float* __restrict__ in,
                                                   float* __restrict__ out) {
#pragma clang fp contract(off)
    const int b    = blockIdx.x;
    const int tid  = threadIdx.x;
    const int lane = tid & 63;
    const int wv   = tid >> 6;    // 0..15
    const float* img = in + (size_t)b * DIM;

    __shared__ uint32_t sbits[NBOXES];                      // 25088 B
    __shared__ uint8_t  cls8[NBOXES];                       //  6272 B
    __shared__ __attribute__((aligned(16))) uint32_t hist[NWAVE][256]; // 16384 B
    __shared__ uint64_t skey[CAND];                         //  2048 B
    __shared__ uint64_t ssort[CAND];                        //  2048 B
    __shared__ uint64_t sel_prefix;
    __shared__ uint32_t sel_rank;
    __shared__ int      nsel;
    __shared__ float cymin[CAND], cxmin[CAND], cymax[CAND], cxmax[CAND];
    __shared__ float carea[CAND], cscore[CAND], ccls[CAND]; //  7168 B
    __shared__ int   klist[MAXOUT];
    __shared__ float rowbuf[MAXOUT * 6];

    // ---------- Phase 1: coalesced score decode ----------
    // 5 lanes x float4 = 80 B = one cell's 20 probs. Lanes 0..59 of a wave read
    // one contiguous 960-B block (12 cells); 3-shuffle tree-max per 5-lane group.
    {
        const float4* pv4 = (const float4*)img;
        const int g = lane / 5;        // group 0..11 (lane 60..63 idle)
        const int k = lane - 5 * g;    // slot in group -> classes 4k..4k+3
        for (int it = 0; it < 17; ++it) {
            int cellbase = (it * NWAVE + wv) * 12;
            if (cellbase >= NCELL) break;
            int cell = cellbase + g;
            bool act = (lane < 60) && (cell < NCELL);
            uint64_t key0 = 0, key1 = 0;
            if (act) {
                float4 pv = pv4[cellbase * 5 + lane];   // fully coalesced
                float2 cf = *(const float2*)(img + BD1 + cell * 2);
                int cb = 4 * k;
                {
                    float c0 = cf.x;
                    uint64_t a = pack_sc(c0 * pv.x, cb + 0);
                    uint64_t d = pack_sc(c0 * pv.y, cb + 1);
                    if (d > a) a = d;
                    d = pack_sc(c0 * pv.z, cb + 2); if (d > a) a = d;
                    d = pack_sc(c0 * pv.w, cb + 3); if (d > a) a = d;
                    key0 = a;
                }
                {
                    float c1 = cf.y;
                    uint64_t a = pack_sc(c1 * pv.x, cb + 0);
                    uint64_t d = pack_sc(c1 * pv.y, cb + 1);
                    if (d > a) a = d;
                    d = pack_sc(c1 * pv.z, cb + 2); if (d > a) a = d;
                    d = pack_sc(c1 * pv.w, cb + 3); if (d > a) a = d;
                    key1 = a;
                }
            }
            // reduce over the 5-lane group; result valid at k==0
            uint64_t t;
            uint64_t k40 = __shfl(key0, lane + 4, 64);
            uint64_t k41 = __shfl(key1, lane + 4, 64);
            t = __shfl(key0, lane + 1, 64); if (t > key0) key0 = t;
            t = __shfl(key1, lane + 1, 64); if (t > key1) key1 = t;
            t = __shfl(key0, lane + 2, 64); if (t > key0) key0 = t;
            t = __shfl(key1, lane + 2, 64); if (t > key1) key1 = t;
            if (k40 > key0) key0 = k40;
            if (k41 > key1) key1 = k41;
            if (act && k == 0) {
                uint32_t b0 = (uint32_t)(key0 >> 8);
                uint32_t b1 = (uint32_t)(key1 >> 8);
                float s0 = __uint_as_float(b0), s1 = __uint_as_float(b1);
                sbits[2 * cell + 0] = (s0 >= 0.1f) ? b0 : 0u;
                sbits[2 * cell + 1] = (s1 >= 0.1f) ? b1 : 0u;
                cls8[2 * cell + 0]  = (uint8_t)(255u - (uint32_t)(key0 & 255u));
                cls8[2 * cell + 1]  = (uint8_t)(255u - (uint32_t)(key1 & 255u));
            }
        }
    }
    if (tid == 0) nsel = 0;
    __syncthreads();

    // ---------- Phase 2: radix-select exact rank-256 key (45-bit, 6x8-bit passes) ----------
    uint64_t prefix = 0;
    uint32_t rank   = CAND;
    for (int pass = 0; pass < 6; pass++) {
        const int shift = 40 - 8 * pass;
        for (int i = tid; i < NWAVE * 256; i += NTHR) ((uint32_t*)hist)[i] = 0;
        __syncthreads();
        for (int idx = tid; idx < NBOXES; idx += NTHR) {
            uint64_t key = make_key(sbits[idx], idx);
            if ((key >> (shift + 8)) == prefix)
                atomicAdd(&hist[wv][(uint32_t)(key >> shift) & 255u], 1u);
        }
        __syncthreads();
        if (wv == 0) {
            uint32_t c0 = 0, c1 = 0, c2 = 0, c3 = 0;
            #pragma unroll
            for (int w = 0; w < NWAVE; w++) {
                uint4 h = ((const uint4*)hist[w])[lane];
                c0 += h.x; c1 += h.y; c2 += h.z; c3 += h.w;
            }
            uint32_t tt = c0 + c1 + c2 + c3;
            uint32_t v = tt;
            #pragma unroll
            for (int off = 1; off < 64; off <<= 1) {
                uint32_t u = __shfl_down(v, off);
                if (lane + off < 64) v += u;
            }
            uint32_t above = v - tt;
            uint32_t s3 = above + c3;
            uint32_t s2 = s3 + c2;
            uint32_t s1 = s2 + c1;
            uint32_t s0 = s1 + c0;
            int dsel = -1; uint32_t g2 = 0;
            if      (above < rank && rank <= s3) { dsel = 4*lane+3; g2 = above; }
            else if (s3    < rank && rank <= s2) { dsel = 4*lane+2; g2 = s3; }
            else if (s2    < rank && rank <= s1) { dsel = 4*lane+1; g2 = s2; }
            else if (s1    < rank && rank <= s0) { dsel = 4*lane+0; g2 = s1; }
            if (dsel >= 0) {
                sel_prefix = (prefix << 8) | (uint64_t)dsel;
                sel_rank   = rank - g2;
            }
        }
        __syncthreads();
        prefix = sel_prefix;
        rank   = sel_rank;
    }
    const uint64_t K256 = prefix;  // exact 256th-largest key

    // ---------- Phase 3: compact the 256 selected keys ----------
    for (int idx = tid; idx < NBOXES; idx += NTHR) {
        uint64_t key = make_key(sbits[idx], idx);
        if (key >= K256) {
            int p = atomicAdd(&nsel, 1);
            if (p < CAND) skey[p] = key;
        }
    }
    if (tid < MAXOUT) klist[tid] = -1;
    __syncthreads();

    // ---------- Phase 4: O(n^2) rank sort (keys unique) + candidate box decode ----------
    if (tid < CAND) {
        uint64_t my = skey[tid];
        int r = 0;
        #pragma unroll 8
        for (int j = 0; j < CAND; j++) r += (skey[j] > my);
        ssort[r] = my;
    }
    __syncthreads();
    if (tid < CAND) {
        uint64_t key = ssort[tid];
        int idx      = 8191 - (int)(key & 0x1FFF);
        uint32_t sb  = (uint32_t)(key >> 13);
        int cell = idx >> 1, bb = idx & 1;
        int i = cell / S, j = cell - i * S;   // i = row (y), j = col (x)
        float4 co = *(const float4*)(img + BD2 + cell * 8 + bb * 4);
        float x  = (co.x + (float)j) / 56.0f;
        float y  = (co.y + (float)i) / 56.0f;
        float wx = co.z * co.z;
        float wy = co.w * co.w;
        float hx = wx * 0.5f, hy = wy * 0.5f;
        float xmin = x - hx, ymin = y - hy, xmax = x + hx, ymax = y + hy;
        cymin[tid] = ymin; cxmin[tid] = xmin; cymax[tid] = ymax; cxmax[tid] = xmax;
        carea[tid] = fmaxf(ymax - ymin, 0.0f) * fmaxf(xmax - xmin, 0.0f);
        cscore[tid] = __uint_as_float(sb);
        ccls[tid]   = (float)cls8[idx];
    }
    __syncthreads();

    // ---------- Phase 5: single-wave greedy NMS (no barriers inside) ----------
    if (wv == 0) {
        float bym[4], bxm[4], byM[4], bxM[4], bar[4];
        #pragma unroll
        for (int s = 0; s < 4; s++) {
            int c = lane + 64 * s;
            bym[s] = cymin[c]; bxm[s] = cxmin[c];
            byM[s] = cymax[c]; bxM[s] = cxmax[c]; bar[s] = carea[c];
        }
        unsigned valid = 0xFu;
        for (int it = 0; it < MAXOUT; it++) {
            int p = -1;
            #pragma unroll
            for (int s = 0; s < 4; s++) {
                if (p < 0) {
                    unsigned long long bl = __ballot((valid >> s) & 1u);
                    if (bl) p = 64 * s + (__ffsll(bl) - 1);
                }
            }
            if (p < 0) break;
            if (lane == 0) klist[it] = p;
            float pym = cymin[p], pxm = cxmin[p];
            float pyM = cymax[p], pxM = cxmax[p], par = carea[p];
            #pragma unroll
            for (int s = 0; s < 4; s++) {
                int c = lane + 64 * s;
                float iy = fmaxf(0.0f, fminf(pyM, byM[s]) - fmaxf(pym, bym[s]));
                float ix = fmaxf(0.0f, fminf(pxM, bxM[s]) - fmaxf(pxm, bxm[s]));
                float inter = iy * ix;
                float uni   = par + bar[s] - inter;
                float iou   = (uni > 0.0f) ? (inter / uni) : 0.0f;
                if (c == p || !(iou <= 0.4f)) valid &= ~(1u << s);
            }
        }
    }
    __syncthreads();

    // ---------- Phase 6: emit 30x6 rows (picks in order, zero-padded) ----------
    if (tid < MAXOUT) {
        int p = klist[tid];
        float* r = &rowbuf[tid * 6];
        if (p >= 0) {
            r[0] = cymin[p]; r[1] = cxmin[p]; r[2] = cymax[p];
            r[3] = cxmax[p]; r[4] = cscore[p]; r[5] = ccls[p];
        } else {
            r[0] = r[1] = r[2] = r[3] = r[4] = r[5] = 0.0f;
        }
    }
    __syncthreads();
    float* ob = out + (size_t)b * (MAXOUT * 6);
    if (tid < MAXOUT * 6) ob[tid] = rowbuf[tid];
}

extern "C" void kernel_launch(void* const* d_in, const int* in_sizes, int n_in,
                              void* d_out, int out_size, void* d_ws, size_t ws_size,
                              hipStream_t stream) {
    const float* in  = (const float*)d_in[0];
    float*       out = (float*)d_out;
    const int B = in_sizes[0] / DIM;   // 256
    det_kernel<<<dim3(B), dim3(NTHR), 0, stream>>>(in, out);
}

// Round 4
// 160.101 us; speedup vs baseline: 1.0365x; 1.0365x over previous
//
#include <hip/hip_runtime.h>
#include <stdint.h>

#define S      56
#define NC     20
#define NCELL  (S*S)          // 3136
#define NBOXES (NCELL*2)      // 6272
#define DIM    94080
#define BD1    62720          // NCELL*NC
#define BD2    68992          // BD1 + NCELL*2
#define CAND   256
#define MAXOUT 30
#define NTHR   1024
#define NWAVE  16
#define NBIN   8192
#define CAP    512

__global__ __launch_bounds__(NTHR) void det_kernel(const float* __restrict__ in,
                                                   float* __restrict__ out) {
#pragma clang fp contract(off)
    const int b    = blockIdx.x;
    const int tid  = threadIdx.x;
    const int lane = tid & 63;
    const int wv   = tid >> 6;
    const float* img = in + (size_t)b * DIM;

    __shared__ uint32_t hist[NBIN];          // 32 KB
    __shared__ uint32_t wsum[NWAVE];
    __shared__ int      bstar_s;
    __shared__ int      nsel;
    __shared__ uint64_t skey[CAP];           // 4 KB
    __shared__ uint64_t ssort[CAND];         // 2 KB
    __shared__ float cymin[CAND], cxmin[CAND], cymax[CAND], cxmax[CAND];
    __shared__ float carea[CAND], cscore[CAND], ccls[CAND];
    __shared__ int   klist[MAXOUT];
    __shared__ float rowbuf[MAXOUT * 6];

    // ---------- zero histogram + init ----------
    ((uint4*)hist)[tid]        = uint4{0,0,0,0};
    ((uint4*)hist)[tid + NTHR] = uint4{0,0,0,0};
    if (tid == 0) nsel = 0;
    if (tid < MAXOUT) klist[tid] = -1;

    // ---------- Phase 1: decode into REGISTERS (no LDS) ----------
    // key = (score_bits << 18) | ((8191-idx) << 5) | cls  — order: score desc, idx asc
    uint64_t key[4][2];
    bool     vld[4];
    #pragma unroll
    for (int i = 0; i < 4; i++) {
        int cell = tid + NTHR * i;
        vld[i] = (cell < NCELL);
        key[i][0] = key[i][1] = 0;
        if (vld[i]) {
            const float4* pv = (const float4*)(img + cell * NC);
            float p[NC];
            #pragma unroll
            for (int q = 0; q < 5; q++) {
                float4 v = pv[q];
                p[4*q+0] = v.x; p[4*q+1] = v.y; p[4*q+2] = v.z; p[4*q+3] = v.w;
            }
            float2 cf = *(const float2*)(img + BD1 + cell * 2);
            #pragma unroll
            for (int bb = 0; bb < 2; bb++) {
                float conf = bb ? cf.y : cf.x;
                float best = conf * p[0];   // rn product; first-occurrence argmax
                int   cls  = 0;
                #pragma unroll
                for (int c = 1; c < NC; c++) {
                    float v = conf * p[c];
                    if (v > best) { best = v; cls = c; }
                }
                uint32_t sb = (best >= 0.1f) ? __float_as_uint(best) : 0u;
                int idx = cell * 2 + bb;
                key[i][bb] = ((uint64_t)sb << 18) | ((uint64_t)(8191 - idx) << 5)
                           | (uint64_t)cls;
            }
        }
    }
    __syncthreads();   // B1: hist zeroed everywhere

    // ---------- Phase 2a: single histogram pass (bin = score_bits >> 17) ----------
    #pragma unroll
    for (int i = 0; i < 4; i++) {
        #pragma unroll
        for (int bb = 0; bb < 2; bb++) {
            uint32_t sb = (uint32_t)(key[i][bb] >> 18);
            if (vld[i] && sb != 0u) atomicAdd(&hist[sb >> 17], 1u);
            unsigned long long zm = __ballot(vld[i] && sb == 0u);
            if (lane == 0 && zm) atomicAdd(&hist[0], (uint32_t)__popcll(zm));
        }
    }
    __syncthreads();   // B2

    // ---------- Phase 2b: block suffix-scan -> threshold bin b* ----------
    uint4 h0 = ((const uint4*)hist)[2*tid];
    uint4 h1 = ((const uint4*)hist)[2*tid+1];
    uint32_t hsum = h0.x+h0.y+h0.z+h0.w + h1.x+h1.y+h1.z+h1.w;
    uint32_t v = hsum;
    #pragma unroll
    for (int off = 1; off < 64; off <<= 1) {
        uint32_t u = __shfl_down(v, off);
        if (lane + off < 64) v += u;
    }
    if (lane == 0) wsum[wv] = v;
    __syncthreads();   // B3
    uint32_t add = 0;
    for (int w = wv + 1; w < NWAVE; w++) add += wsum[w];
    uint32_t Sm    = v + add;       // elems in bins >= 8*tid
    uint32_t above = Sm - hsum;     // elems in bins >= 8*(tid+1)
    if (above < CAND && CAND <= Sm) {   // exactly one thread
        uint32_t hh[8] = {h1.w, h1.z, h1.y, h1.x, h0.w, h0.z, h0.y, h0.x};
        uint32_t g = above;
        int bsel = 8 * tid;
        #pragma unroll
        for (int j = 0; j < 8; j++) {
            if (g + hh[j] >= CAND) { bsel = 8 * tid + (7 - j); break; }
            g += hh[j];
        }
        bstar_s = bsel;
    }
    __syncthreads();   // B4
    const uint32_t bstar = (uint32_t)bstar_s;

    // ---------- Phase 2c: compact superset (bin >= b*), wave-aggregated ----------
    #pragma unroll
    for (int i = 0; i < 4; i++) {
        #pragma unroll
        for (int bb = 0; bb < 2; bb++) {
            bool pred = vld[i] && ((uint32_t)(key[i][bb] >> 35) >= bstar);
            unsigned long long mask = __ballot(pred);
            if (mask) {
                int leader = __ffsll(mask) - 1;
                int base = 0;
                if (lane == leader) base = atomicAdd(&nsel, (int)__popcll(mask));
                base = __shfl(base, leader);
                if (pred) {
                    int pos = base + (int)__popcll(mask & ((1ull << lane) - 1ull));
                    if (pos < CAP) skey[pos] = key[i][bb];
                }
            }
        }
    }
    __syncthreads();   // B5

    // ---------- Phase 3: rank-sort top-256 of the M-superset ----------
    const int M = (nsel < CAP) ? nsel : CAP;
    if (tid < M) {
        uint64_t my = skey[tid];
        int r = 0;
        #pragma unroll 4
        for (int j = 0; j < M; j++) r += (skey[j] > my);   // broadcast LDS reads
        if (r < CAND) ssort[r] = my;
    }
    __syncthreads();   // B6

    // ---------- Phase 4: decode the 256 candidate boxes ----------
    if (tid < CAND) {
        uint64_t k = ssort[tid];
        int idx      = 8191 - (int)((k >> 5) & 0x1FFF);
        int cls      = (int)(k & 31u);
        uint32_t sb  = (uint32_t)(k >> 18);
        int cell = idx >> 1, bb = idx & 1;
        int i = cell / S, j = cell - i * S;   // i = row (y), j = col (x)
        float4 co = *(const float4*)(img + BD2 + cell * 8 + bb * 4);
        float x  = (co.x + (float)j) / 56.0f;
        float y  = (co.y + (float)i) / 56.0f;
        float wx = co.z * co.z;
        float wy = co.w * co.w;
        float hx = wx * 0.5f, hy = wy * 0.5f;
        float xmin = x - hx, ymin = y - hy, xmax = x + hx, ymax = y + hy;
        cymin[tid] = ymin; cxmin[tid] = xmin; cymax[tid] = ymax; cxmax[tid] = xmax;
        carea[tid] = fmaxf(ymax - ymin, 0.0f) * fmaxf(xmax - xmin, 0.0f);
        cscore[tid] = __uint_as_float(sb);
        ccls[tid]   = (float)cls;
    }
    __syncthreads();   // B7

    // ---------- Phase 5: single-wave greedy NMS (lane owns 4 consecutive) ----------
    if (wv == 0) {
        float bym[4], bxm[4], byM[4], bxM[4], bar[4];
        #pragma unroll
        for (int s = 0; s < 4; s++) {
            int c = 4 * lane + s;
            bym[s] = cymin[c]; bxm[s] = cxmin[c];
            byM[s] = cymax[c]; bxM[s] = cxmax[c]; bar[s] = carea[c];
        }
        unsigned vmask = 0xFu;
        for (int it = 0; it < MAXOUT; it++) {
            unsigned long long mk = __ballot(vmask != 0u);
            if (!mk) break;
            int l0 = __ffsll(mk) - 1;
            int vb = __shfl((int)vmask, l0);
            int p  = 4 * l0 + (__ffs(vb) - 1);   // first valid candidate overall
            if (lane == 0) klist[it] = p;
            float pym = cymin[p], pxm = cxmin[p];
            float pyM = cymax[p], pxM = cxmax[p], par = carea[p];
            #pragma unroll
            for (int s = 0; s < 4; s++) {
                int c = 4 * lane + s;
                float iy = fmaxf(0.0f, fminf(pyM, byM[s]) - fmaxf(pym, bym[s]));
                float ix = fmaxf(0.0f, fminf(pxM, bxM[s]) - fmaxf(pxm, bxm[s]));
                float inter = iy * ix;
                float uni   = par + bar[s] - inter;
                float iou   = (uni > 0.0f) ? (inter / uni) : 0.0f;  // exact IEEE div
                if (c == p || !(iou <= 0.4f)) vmask &= ~(1u << s);
            }
        }
    }
    __syncthreads();   // B8

    // ---------- Phase 6: emit 30x6 rows ----------
    if (tid < MAXOUT) {
        int p = klist[tid];
        float* r = &rowbuf[tid * 6];
        if (p >= 0) {
            r[0] = cymin[p]; r[1] = cxmin[p]; r[2] = cymax[p];
            r[3] = cxmax[p]; r[4] = cscore[p]; r[5] = ccls[p];
        } else {
            r[0] = r[1] = r[2] = r[3] = r[4] = r[5] = 0.0f;
        }
    }
    __syncthreads();   // B9
    float* ob = out + (size_t)b * (MAXOUT * 6);
    if (tid < MAXOUT * 6) ob[tid] = rowbuf[tid];
}

extern "C" void kernel_launch(void* const* d_in, const int* in_sizes, int n_in,
                              void* d_out, int out_size, void* d_ws, size_t ws_size,
                              hipStream_t stream) {
    const float* in  = (const float*)d_in[0];
    float*       out = (float*)d_out;
    const int B = in_sizes[0] / DIM;   // 256
    det_kernel<<<dim3(B), dim3(NTHR), 0, stream>>>(in, out);
}